// Round 2
// baseline (302.342 us; speedup 1.0000x reference)
//
#include <hip/hip_runtime.h>
#include <cstddef>

#define NN 12288
#define FD 512
#define H1 32
#define H2 16

// ---------------- degree ----------------
__global__ void k_degree(const int* __restrict__ src, const int* __restrict__ dst,
                         float* __restrict__ deg_out, float* __restrict__ deg_in, int E) {
    int e = blockIdx.x * 256 + threadIdx.x;
    if (e < E) {
        atomicAdd(&deg_out[src[e]], 1.0f);
        atomicAdd(&deg_in[dst[e]], 1.0f);
    }
}

// ---------------- norms ----------------
__global__ void k_norms(const float* __restrict__ deg_out, const float* __restrict__ deg_in,
                        float* __restrict__ n_src, float* __restrict__ n_dst) {
    int i = blockIdx.x * 256 + threadIdx.x;
    if (i < NN) {
        // self-loops guarantee deg >= 1
        n_src[i] = rsqrtf(deg_out[i]);
        n_dst[i] = rsqrtf(deg_in[i]);
    }
}

// ---------------- P = n_src * (feat @ W1) ----------------
// block 256: 64 rows, thread = (row_local = tid>>2, col-group = (tid&3)*8)
__global__ __launch_bounds__(256) void k_gemm1(const float* __restrict__ feat,
                                               const float* __restrict__ W1,
                                               const float* __restrict__ n_src,
                                               float* __restrict__ P) {
    __shared__ float Wlds[FD * H1]; // 64 KB, k-major [k][c]
    int tid = threadIdx.x;
    for (int t = tid; t < FD * H1 / 4; t += 256) {
        ((float4*)Wlds)[t] = ((const float4*)W1)[t];
    }
    __syncthreads();

    int row = blockIdx.x * 64 + (tid >> 2);
    int cg  = (tid & 3) * 8;
    float acc[8] = {};
    const float4* f4 = (const float4*)(feat + (size_t)row * FD);
#pragma unroll 4
    for (int k4 = 0; k4 < FD / 4; ++k4) {
        float4 f = f4[k4];
        const float* w = &Wlds[(k4 * 4) * H1 + cg];
#pragma unroll
        for (int j = 0; j < 8; ++j) {
            acc[j] += f.x * w[j] + f.y * w[H1 + j] + f.z * w[2 * H1 + j] + f.w * w[3 * H1 + j];
        }
    }
    float ns = n_src[row];
#pragma unroll
    for (int j = 0; j < 8; ++j) P[(size_t)row * H1 + cg + j] = acc[j] * ns;
}

// ---------------- SpMM: agg[dst] += X[src], 32 lanes per edge ----------------
__global__ void k_spmm(const int* __restrict__ src, const int* __restrict__ dst,
                       const float* __restrict__ X, float* __restrict__ agg, int E) {
    int gid = blockIdx.x * 256 + threadIdx.x;
    int e = gid >> 5;
    int j = gid & 31;
    if (e < E) {
        int s = src[e];
        int d = dst[e];
        float v = X[(size_t)s * H1 + j];
        atomicAdd(&agg[(size_t)d * H1 + j], v);
    }
}

// ---------------- h1s = n_src * relu(n_dst*agg1 + b1) ----------------
__global__ void k_h1(const float* __restrict__ agg1, const float* __restrict__ n_dst,
                     const float* __restrict__ n_src, const float* __restrict__ b1,
                     float* __restrict__ h1s) {
    int gid = blockIdx.x * 256 + threadIdx.x; // NN*32 total
    int i = gid >> 5, j = gid & 31;
    float h = fmaxf(agg1[gid] * n_dst[i] + b1[j], 0.0f);
    h1s[gid] = h * n_src[i];
}

// ---------------- mu/logvar = (n_dst*agg2) @ W2/W3 + b2/b3 ----------------
__global__ __launch_bounds__(256) void k_mulv(const float* __restrict__ agg2,
                                              const float* __restrict__ n_dst,
                                              const float* __restrict__ W2, const float* __restrict__ b2,
                                              const float* __restrict__ W3, const float* __restrict__ b3,
                                              float* __restrict__ mu, float* __restrict__ lv) {
    __shared__ float W2l[H1 * H2], W3l[H1 * H2];
    int tid = threadIdx.x;
    for (int t = tid; t < H1 * H2; t += 256) { W2l[t] = W2[t]; W3l[t] = W3[t]; }
    __syncthreads();
    int gid = blockIdx.x * 256 + tid;
    int i = gid >> 4, c = gid & 15;
    if (i < NN) {
        float nd = n_dst[i];
        float a_mu = b2[c], a_lv = b3[c];
#pragma unroll
        for (int k = 0; k < H1; ++k) {
            float a = agg2[(size_t)i * H1 + k] * nd;
            a_mu += a * W2l[k * H2 + c];
            a_lv += a * W3l[k * H2 + c];
        }
        mu[gid] = a_mu;
        lv[gid] = a_lv;
    }
}

// ---------------- adj = mu @ mu^T, 128x128 tile, 8x8 per thread ----------------
#define TILE 128
__global__ __launch_bounds__(256) void k_adj(const float* __restrict__ mu, float* __restrict__ out) {
    __shared__ float Al[TILE][17];
    __shared__ float Bl[TILE][17];
    int tid = threadIdx.x;
    int i0 = blockIdx.y * TILE;
    int j0 = blockIdx.x * TILE;

    {
        int row = tid >> 1;
        int h8  = (tid & 1) * 8;
        float4 a0 = *(const float4*)&mu[(size_t)(i0 + row) * H2 + h8];
        float4 a1 = *(const float4*)&mu[(size_t)(i0 + row) * H2 + h8 + 4];
        Al[row][h8 + 0] = a0.x; Al[row][h8 + 1] = a0.y; Al[row][h8 + 2] = a0.z; Al[row][h8 + 3] = a0.w;
        Al[row][h8 + 4] = a1.x; Al[row][h8 + 5] = a1.y; Al[row][h8 + 6] = a1.z; Al[row][h8 + 7] = a1.w;
        float4 b0 = *(const float4*)&mu[(size_t)(j0 + row) * H2 + h8];
        float4 b1 = *(const float4*)&mu[(size_t)(j0 + row) * H2 + h8 + 4];
        Bl[row][h8 + 0] = b0.x; Bl[row][h8 + 1] = b0.y; Bl[row][h8 + 2] = b0.z; Bl[row][h8 + 3] = b0.w;
        Bl[row][h8 + 4] = b1.x; Bl[row][h8 + 5] = b1.y; Bl[row][h8 + 6] = b1.z; Bl[row][h8 + 7] = b1.w;
    }
    __syncthreads();

    int tx = tid & 15;   // j dimension (coalescing)
    int ty = tid >> 4;   // i dimension
    float acc[8][8] = {};
#pragma unroll
    for (int k = 0; k < H2; ++k) {
        float a[8], b[8];
#pragma unroll
        for (int ii = 0; ii < 8; ++ii) a[ii] = Al[ty * 8 + ii][k];
#pragma unroll
        for (int jj = 0; jj < 8; ++jj) b[jj] = Bl[tx * 8 + jj][k];
#pragma unroll
        for (int ii = 0; ii < 8; ++ii)
#pragma unroll
            for (int jj = 0; jj < 8; ++jj) acc[ii][jj] += a[ii] * b[jj];
    }

#pragma unroll
    for (int ii = 0; ii < 8; ++ii) {
        size_t row = (size_t)(i0 + ty * 8 + ii);
        float4 v0 = make_float4(acc[ii][0], acc[ii][1], acc[ii][2], acc[ii][3]);
        float4 v1 = make_float4(acc[ii][4], acc[ii][5], acc[ii][6], acc[ii][7]);
        *(float4*)&out[row * NN + j0 + tx * 8 + 0] = v0;
        *(float4*)&out[row * NN + j0 + tx * 8 + 4] = v1;
    }
}

extern "C" void kernel_launch(void* const* d_in, const int* in_sizes, int n_in,
                              void* d_out, int out_size, void* d_ws, size_t ws_size,
                              hipStream_t stream) {
    const float* feat = (const float*)d_in[0];
    const int*   src  = (const int*)d_in[1];
    const int*   dst  = (const int*)d_in[2];
    const float* W1   = (const float*)d_in[3];
    const float* b1   = (const float*)d_in[4];
    const float* W2   = (const float*)d_in[5];
    const float* b2   = (const float*)d_in[6];
    const float* W3   = (const float*)d_in[7];
    const float* b3   = (const float*)d_in[8];
    int E = in_sizes[1];

    float* ws = (float*)d_ws;
    float* deg_out = ws;                 // [NN]
    float* deg_in  = ws + NN;            // [NN]
    float* n_src   = ws + 2 * NN;        // [NN]
    float* n_dst   = ws + 3 * NN;        // [NN]
    float* P       = ws + 4 * NN;        // [NN*H1]
    float* agg1    = ws + 4 * NN + NN * H1;       // [NN*H1]
    float* h1s     = ws + 4 * NN + 2 * NN * H1;   // [NN*H1]
    float* agg2    = ws + 4 * NN + 3 * NN * H1;   // [NN*H1]

    float* adj = (float*)d_out;                       // [NN*NN]
    float* mu  = adj + (size_t)NN * NN;               // [NN*H2]
    float* lv  = mu + (size_t)NN * H2;                // [NN*H2]

    // zero accumulators (graph-capture safe)
    hipMemsetAsync(deg_out, 0, 2 * NN * sizeof(float), stream);
    hipMemsetAsync(agg1, 0, (size_t)NN * H1 * sizeof(float), stream);
    hipMemsetAsync(agg2, 0, (size_t)NN * H1 * sizeof(float), stream);

    k_degree<<<(E + 255) / 256, 256, 0, stream>>>(src, dst, deg_out, deg_in, E);
    k_norms<<<(NN + 255) / 256, 256, 0, stream>>>(deg_out, deg_in, n_src, n_dst);
    k_gemm1<<<NN / 64, 256, 0, stream>>>(feat, W1, n_src, P);
    {
        long long work = (long long)E * 32;
        int blocks = (int)((work + 255) / 256);
        k_spmm<<<blocks, 256, 0, stream>>>(src, dst, P, agg1, E);
    }
    k_h1<<<NN * 32 / 256, 256, 0, stream>>>(agg1, n_dst, n_src, b1, h1s);
    {
        long long work = (long long)E * 32;
        int blocks = (int)((work + 255) / 256);
        k_spmm<<<blocks, 256, 0, stream>>>(src, dst, h1s, agg2, E);
    }
    k_mulv<<<NN * 16 / 256, 256, 0, stream>>>(agg2, n_dst, W2, b2, W3, b3, mu, lv);

    dim3 grid(NN / TILE, NN / TILE);
    k_adj<<<grid, 256, 0, stream>>>(mu, adj);
}

// Round 3
// 269.479 us; speedup vs baseline: 1.1220x; 1.1220x over previous
//
#include <hip/hip_runtime.h>
#include <cstddef>

#define NN 12288
#define FD 512
#define H1 32
#define H2 16

// ---------------- degree histograms (int atomics) ----------------
__global__ void k_degree(const int* __restrict__ src, const int* __restrict__ dst,
                         int* __restrict__ deg_out, int* __restrict__ deg_in, int E) {
    int e = blockIdx.x * 256 + threadIdx.x;
    if (e < E) {
        atomicAdd(&deg_out[src[e]], 1);
        atomicAdd(&deg_in[dst[e]], 1);
    }
}

// ---------------- single-block scan + norms + zero cnt ----------------
// row_ptr = exclusive_scan(deg_in); n_src = rsqrt(deg_out); n_dst = rsqrt(deg_in);
// cnt (aliases deg_out) zeroed AFTER reading.
__global__ __launch_bounds__(256) void k_scan(int* __restrict__ deg_out_cnt,
                                              const int* __restrict__ deg_in,
                                              int* __restrict__ row_ptr,
                                              float* __restrict__ n_src,
                                              float* __restrict__ n_dst) {
    __shared__ int part[257];
    int tid = threadIdx.x;
    const int CH = NN / 256; // 48
    int base = tid * CH;
    int local[CH];
    int s = 0;
    for (int t = 0; t < CH; ++t) { local[t] = s; s += deg_in[base + t]; }
    part[tid + 1] = s;
    __syncthreads();
    if (tid == 0) {
        part[0] = 0;
        for (int t = 1; t <= 256; ++t) part[t] += part[t - 1];
    }
    __syncthreads();
    int off0 = part[tid];
    for (int t = 0; t < CH; ++t) row_ptr[base + t] = off0 + local[t];
    if (tid == 255) row_ptr[NN] = off0 + s;

    // norms + zero cnt (self-loops guarantee deg >= 1)
    for (int i = tid; i < NN; i += 256) {
        int dout = deg_out_cnt[i];
        n_src[i] = rsqrtf((float)dout);
        n_dst[i] = rsqrtf((float)deg_in[i]);
        deg_out_cnt[i] = 0; // becomes cnt for scatter
    }
}

// ---------------- scatter edges into dst-sorted order ----------------
__global__ void k_scatter(const int* __restrict__ src, const int* __restrict__ dst,
                          const int* __restrict__ row_ptr, int* __restrict__ cnt,
                          int* __restrict__ sorted_src, int E) {
    int e = blockIdx.x * 256 + threadIdx.x;
    if (e < E) {
        int d = dst[e];
        int pos = row_ptr[d] + atomicAdd(&cnt[d], 1);
        sorted_src[pos] = src[e];
    }
}

// ---------------- P = n_src * (feat @ W1) ----------------
__global__ __launch_bounds__(256) void k_gemm1(const float* __restrict__ feat,
                                               const float* __restrict__ W1,
                                               const float* __restrict__ n_src,
                                               float* __restrict__ P) {
    __shared__ float Wlds[FD * H1]; // 64 KB, k-major [k][c]
    int tid = threadIdx.x;
    for (int t = tid; t < FD * H1 / 4; t += 256) {
        ((float4*)Wlds)[t] = ((const float4*)W1)[t];
    }
    __syncthreads();

    int row = blockIdx.x * 64 + (tid >> 2);
    int cg  = (tid & 3) * 8;
    float acc[8] = {};
    const float4* f4 = (const float4*)(feat + (size_t)row * FD);
#pragma unroll 4
    for (int k4 = 0; k4 < FD / 4; ++k4) {
        float4 f = f4[k4];
        const float* w = &Wlds[(k4 * 4) * H1 + cg];
#pragma unroll
        for (int j = 0; j < 8; ++j) {
            acc[j] += f.x * w[j] + f.y * w[H1 + j] + f.z * w[2 * H1 + j] + f.w * w[3 * H1 + j];
        }
    }
    float ns = n_src[row];
#pragma unroll
    for (int j = 0; j < 8; ++j) P[(size_t)row * H1 + cg + j] = acc[j] * ns;
}

// ---------------- agg1: CSR pull + fused ReLU epilogue ----------------
// h1s[i][j] = n_src[i] * relu(n_dst[i] * sum_{e in in(i)} P[src[e]][j] + b1[j])
__global__ __launch_bounds__(256) void k_agg1(const int* __restrict__ row_ptr,
                                              const int* __restrict__ sorted_src,
                                              const float* __restrict__ P,
                                              const float* __restrict__ n_src,
                                              const float* __restrict__ n_dst,
                                              const float* __restrict__ b1,
                                              float* __restrict__ h1s) {
    int r = blockIdx.x * 8 + (threadIdx.x >> 5);
    int j = threadIdx.x & 31;
    int beg = row_ptr[r], end = row_ptr[r + 1];
    float s = 0.0f;
    int e = beg;
    for (; e + 1 < end; e += 2) {
        int s0 = sorted_src[e];
        int s1 = sorted_src[e + 1];
        s += P[(size_t)s0 * H1 + j];
        s += P[(size_t)s1 * H1 + j];
    }
    if (e < end) s += P[(size_t)sorted_src[e] * H1 + j];
    float h = fmaxf(s * n_dst[r] + b1[j], 0.0f);
    h1s[(size_t)r * H1 + j] = h * n_src[r];
}

// ---------------- agg2: CSR pull + fused mu/logvar projection ----------------
__global__ __launch_bounds__(256) void k_agg2(const int* __restrict__ row_ptr,
                                              const int* __restrict__ sorted_src,
                                              const float* __restrict__ h1s,
                                              const float* __restrict__ n_dst,
                                              const float* __restrict__ W2, const float* __restrict__ b2,
                                              const float* __restrict__ W3, const float* __restrict__ b3,
                                              float* __restrict__ mu, float* __restrict__ lv) {
    __shared__ float W2l[H1 * H2], W3l[H1 * H2];
    __shared__ float S[8][H1];
    int tid = threadIdx.x;
    for (int t = tid; t < H1 * H2; t += 256) { W2l[t] = W2[t]; W3l[t] = W3[t]; }

    int r0 = blockIdx.x * 8;
    int rl = tid >> 5, j = tid & 31;
    int r = r0 + rl;
    int beg = row_ptr[r], end = row_ptr[r + 1];
    float s = 0.0f;
    int e = beg;
    for (; e + 1 < end; e += 2) {
        int s0 = sorted_src[e];
        int s1 = sorted_src[e + 1];
        s += h1s[(size_t)s0 * H1 + j];
        s += h1s[(size_t)s1 * H1 + j];
    }
    if (e < end) s += h1s[(size_t)sorted_src[e] * H1 + j];
    S[rl][j] = s * n_dst[r];
    __syncthreads();

    // 8 rows x 16 cols x {mu, lv} = 256 outputs, one per thread
    int rr = tid >> 5;
    int c = tid & 15;
    bool is_lv = (tid & 16) != 0;
    const float* W = is_lv ? W3l : W2l;
    float acc = is_lv ? b3[c] : b2[c];
#pragma unroll
    for (int k = 0; k < H1; ++k) acc += S[rr][k] * W[k * H2 + c];
    float* o = is_lv ? lv : mu;
    o[(size_t)(r0 + rr) * H2 + c] = acc;
}

// ---------------- adj = mu @ mu^T, 128x128 tile, 8x8 per thread ----------------
#define TILE 128
__global__ __launch_bounds__(256) void k_adj(const float* __restrict__ mu, float* __restrict__ out) {
    __shared__ float Al[TILE][17];
    __shared__ float Bl[TILE][17];
    int tid = threadIdx.x;
    int i0 = blockIdx.y * TILE;
    int j0 = blockIdx.x * TILE;

    {
        int row = tid >> 1;
        int h8  = (tid & 1) * 8;
        float4 a0 = *(const float4*)&mu[(size_t)(i0 + row) * H2 + h8];
        float4 a1 = *(const float4*)&mu[(size_t)(i0 + row) * H2 + h8 + 4];
        Al[row][h8 + 0] = a0.x; Al[row][h8 + 1] = a0.y; Al[row][h8 + 2] = a0.z; Al[row][h8 + 3] = a0.w;
        Al[row][h8 + 4] = a1.x; Al[row][h8 + 5] = a1.y; Al[row][h8 + 6] = a1.z; Al[row][h8 + 7] = a1.w;
        float4 b0 = *(const float4*)&mu[(size_t)(j0 + row) * H2 + h8];
        float4 b1 = *(const float4*)&mu[(size_t)(j0 + row) * H2 + h8 + 4];
        Bl[row][h8 + 0] = b0.x; Bl[row][h8 + 1] = b0.y; Bl[row][h8 + 2] = b0.z; Bl[row][h8 + 3] = b0.w;
        Bl[row][h8 + 4] = b1.x; Bl[row][h8 + 5] = b1.y; Bl[row][h8 + 6] = b1.z; Bl[row][h8 + 7] = b1.w;
    }
    __syncthreads();

    int tx = tid & 15;   // j (coalescing)
    int ty = tid >> 4;   // i
    float acc[8][8] = {};
#pragma unroll
    for (int k = 0; k < H2; ++k) {
        float a[8], b[8];
#pragma unroll
        for (int ii = 0; ii < 8; ++ii) a[ii] = Al[ty * 8 + ii][k];
#pragma unroll
        for (int jj = 0; jj < 8; ++jj) b[jj] = Bl[tx * 8 + jj][k];
#pragma unroll
        for (int ii = 0; ii < 8; ++ii)
#pragma unroll
            for (int jj = 0; jj < 8; ++jj) acc[ii][jj] += a[ii] * b[jj];
    }

#pragma unroll
    for (int ii = 0; ii < 8; ++ii) {
        size_t row = (size_t)(i0 + ty * 8 + ii);
        float4 v0 = make_float4(acc[ii][0], acc[ii][1], acc[ii][2], acc[ii][3]);
        float4 v1 = make_float4(acc[ii][4], acc[ii][5], acc[ii][6], acc[ii][7]);
        *(float4*)&out[row * NN + j0 + tx * 8 + 0] = v0;
        *(float4*)&out[row * NN + j0 + tx * 8 + 4] = v1;
    }
}

extern "C" void kernel_launch(void* const* d_in, const int* in_sizes, int n_in,
                              void* d_out, int out_size, void* d_ws, size_t ws_size,
                              hipStream_t stream) {
    const float* feat = (const float*)d_in[0];
    const int*   src  = (const int*)d_in[1];
    const int*   dst  = (const int*)d_in[2];
    const float* W1   = (const float*)d_in[3];
    const float* b1   = (const float*)d_in[4];
    const float* W2   = (const float*)d_in[5];
    const float* b2   = (const float*)d_in[6];
    const float* W3   = (const float*)d_in[7];
    const float* b3   = (const float*)d_in[8];
    int E = in_sizes[1]; // 405504

    // workspace layout (ints first, then floats; all offsets 64-elem aligned)
    int* iws = (int*)d_ws;
    int* deg_out_cnt = iws;                 // [NN]  (deg_out, then reused as scatter cnt)
    int* deg_in      = iws + NN;            // [NN]
    int* row_ptr     = iws + 2 * NN;        // [NN+1] (padded to NN+64)
    int* sorted_src  = iws + 3 * NN + 64;   // [E]
    float* fws   = (float*)(iws + 3 * NN + 64 + E);
    float* n_src = fws;                     // [NN]
    float* n_dst = fws + NN;                // [NN]
    float* P     = fws + 2 * NN;            // [NN*H1]
    float* h1s   = fws + 2 * NN + NN * H1;  // [NN*H1]

    float* adj = (float*)d_out;             // [NN*NN]
    float* mu  = adj + (size_t)NN * NN;     // [NN*H2]
    float* lv  = mu + (size_t)NN * H2;      // [NN*H2]

    hipMemsetAsync(deg_out_cnt, 0, 2 * NN * sizeof(int), stream); // deg_out + deg_in

    int eb = (E + 255) / 256;
    k_degree<<<eb, 256, 0, stream>>>(src, dst, deg_out_cnt, deg_in, E);
    k_scan<<<1, 256, 0, stream>>>(deg_out_cnt, deg_in, row_ptr, n_src, n_dst);
    k_scatter<<<eb, 256, 0, stream>>>(src, dst, row_ptr, deg_out_cnt, sorted_src, E);
    k_gemm1<<<NN / 64, 256, 0, stream>>>(feat, W1, n_src, P);
    k_agg1<<<NN / 8, 256, 0, stream>>>(row_ptr, sorted_src, P, n_src, n_dst, b1, h1s);
    k_agg2<<<NN / 8, 256, 0, stream>>>(row_ptr, sorted_src, h1s, n_dst, W2, b2, W3, b3, mu, lv);

    dim3 grid(NN / TILE, NN / TILE);
    k_adj<<<grid, 256, 0, stream>>>(mu, adj);
}